// Round 1
// baseline (525.442 us; speedup 1.0000x reference)
//
#include <hip/hip_runtime.h>

// Problem constants (reference: B,H,L,D = 2,16,2048,64)
#define BB 2
#define HH 16
#define LL 2048
#define DD 64
constexpr int BH = BB * HH;   // 32 heads total
constexpr int NT = LL / 64;   // 32 column/row tiles of 64

// ---------------------------------------------------------------------------
// Kernel 1: feature map  out = relu(x @ W) per head.
// grid.x = BH*NT blocks, 256 threads. 64-row tile, 4x4 reg tile per thread.
// ---------------------------------------------------------------------------
__global__ __launch_bounds__(256) void fmap_kernel(
    const float* __restrict__ x, const float* __restrict__ W,
    float* __restrict__ out)
{
    __shared__ float sXT[64][64];   // x tile transposed: sXT[d][r]
    __shared__ float sW[64][64];    // W row-major: sW[d][e]
    int bx = blockIdx.x;
    int bh = bx / NT, rb = bx % NT;
    int h = bh % HH;
    const float* xp = x + (size_t)bh * LL * DD + (size_t)rb * 64 * DD;
    const float* wp = W + (size_t)h * DD * DD;
    float* op = out + (size_t)bh * LL * DD + (size_t)rb * 64 * DD;

    int tid = threadIdx.x;
    int r = tid >> 2, c0 = (tid & 3) * 16;
    for (int u = 0; u < 16; u += 4) {
        float4 t = *(const float4*)(xp + r * DD + c0 + u);
        sXT[c0 + u + 0][r] = t.x; sXT[c0 + u + 1][r] = t.y;
        sXT[c0 + u + 2][r] = t.z; sXT[c0 + u + 3][r] = t.w;
        *(float4*)(&sW[r][c0 + u]) = *(const float4*)(wp + r * DD + c0 + u);
    }
    __syncthreads();

    int ty = tid >> 4, tx = tid & 15;
    float acc[4][4] = {};
    #pragma unroll 4
    for (int d = 0; d < 64; ++d) {
        float4 a = *(const float4*)(&sXT[d][ty * 4]);
        float4 b = *(const float4*)(&sW[d][tx * 4]);
        float av[4] = {a.x, a.y, a.z, a.w};
        float bv[4] = {b.x, b.y, b.z, b.w};
        #pragma unroll
        for (int j = 0; j < 4; ++j)
            #pragma unroll
            for (int i = 0; i < 4; ++i)
                acc[j][i] = fmaf(av[j], bv[i], acc[j][i]);
    }
    #pragma unroll
    for (int j = 0; j < 4; ++j) {
        float4 o;
        o.x = fmaxf(acc[j][0], 0.f);
        o.y = fmaxf(acc[j][1], 0.f);
        o.z = fmaxf(acc[j][2], 0.f);
        o.w = fmaxf(acc[j][3], 0.f);
        *(float4*)(op + (size_t)(ty * 4 + j) * DD + tx * 4) = o;
    }
}

// ---------------------------------------------------------------------------
// Kernel 2: per-head inclusive prefix sum of fk over L (for row-normalizers).
// One block per head, 1024 threads = 16 waves; lane = dim, wave = row chunk.
// ---------------------------------------------------------------------------
__global__ __launch_bounds__(1024) void csum_kernel(
    const float* __restrict__ fk, float* __restrict__ cs)
{
    __shared__ float chunk[16][64];
    int bh = blockIdx.x;
    int w = threadIdx.x >> 6;
    int d = threadIdx.x & 63;
    const float* fp = fk + (size_t)bh * LL * DD;
    float* cp = cs + (size_t)bh * LL * DD;
    const int CH = LL / 16;   // 128 rows per wave

    float s = 0.f;
    for (int i = 0; i < CH; ++i) s += fp[(size_t)(w * CH + i) * DD + d];
    chunk[w][d] = s;
    __syncthreads();
    float run = 0.f;
    for (int w2 = 0; w2 < w; ++w2) run += chunk[w2][d];
    for (int i = 0; i < CH; ++i) {
        run += fp[(size_t)(w * CH + i) * DD + d];
        cp[(size_t)(w * CH + i) * DD + d] = run;
    }
}

// ---------------------------------------------------------------------------
// Kernel 3: main fused kernel.
// One block per (head, 64-row block). Computes inv rowsums from cumsum,
// then loops column tiles j<=i: S = fq@fk^T (reg-tiled), mask, scale,
// write attn, stash S^T in LDS, PV accumulate. Finally zero-fills tiles
// above the diagonal and writes `out`.
// ---------------------------------------------------------------------------
__global__ __launch_bounds__(256) void attn_kernel(
    const float* __restrict__ fq, const float* __restrict__ fk,
    const float* __restrict__ cs, const float* __restrict__ v,
    float* __restrict__ outO, float* __restrict__ outA)
{
    __shared__ float sQT[64][64];   // fq tile transposed: sQT[d][r]
    __shared__ float sKT[64][64];   // fk tile transposed: sKT[d][c]
    __shared__ float sV[64][64];    // v tile: sV[c][e]
    __shared__ float sS[64][68];    // scaled S transposed: sS[c][r] (pad 68)
    __shared__ float sInv[64];

    int bx = blockIdx.x;
    int bh = bx >> 5;       // / NT
    int rblk = bx & 31;     // % NT
    int brow = rblk * 64;
    int tid = threadIdx.x;
    int ty = tid >> 4, tx = tid & 15;

    const float* fqp = fq + (size_t)bh * LL * DD + (size_t)brow * DD;
    const float* fkp = fk + (size_t)bh * LL * DD;
    const float* csp = cs + (size_t)bh * LL * DD + (size_t)brow * DD;
    const float* vp  = v  + (size_t)bh * LL * DD;
    float* aout = outA + (size_t)bh * LL * LL + (size_t)brow * LL;

    // load fq tile transposed
    {
        int r = tid >> 2, c0 = (tid & 3) * 16;
        for (int u = 0; u < 16; u += 4) {
            float4 t = *(const float4*)(fqp + r * DD + c0 + u);
            sQT[c0 + u + 0][r] = t.x; sQT[c0 + u + 1][r] = t.y;
            sQT[c0 + u + 2][r] = t.z; sQT[c0 + u + 3][r] = t.w;
        }
    }
    __syncthreads();

    // inv rowsum: rowsum_i = fq_i . cumsum_fk_i ; 4 threads per row
    {
        int r = tid >> 2, p = tid & 3;
        float partial = 0.f;
        for (int u = 0; u < 16; u += 4) {
            float4 c4 = *(const float4*)(csp + r * DD + p * 16 + u);
            partial += sQT[p * 16 + u + 0][r] * c4.x
                     + sQT[p * 16 + u + 1][r] * c4.y
                     + sQT[p * 16 + u + 2][r] * c4.z
                     + sQT[p * 16 + u + 3][r] * c4.w;
        }
        partial += __shfl_xor(partial, 1);
        partial += __shfl_xor(partial, 2);
        if (p == 0) sInv[r] = 1.0f / partial;
    }
    __syncthreads();
    float rInv[4];
    #pragma unroll
    for (int j = 0; j < 4; ++j) rInv[j] = sInv[ty * 4 + j];

    float acc[4][4] = {};   // out accumulator: rows 4ty.., dims 4tx..

    for (int ct = 0; ct <= rblk; ++ct) {
        int bcol = ct * 64;
        // stage fk tile (transposed) and v tile
        {
            int r = tid >> 2, c0 = (tid & 3) * 16;
            for (int u = 0; u < 16; u += 4) {
                float4 t = *(const float4*)(fkp + (size_t)(bcol + r) * DD + c0 + u);
                sKT[c0 + u + 0][r] = t.x; sKT[c0 + u + 1][r] = t.y;
                sKT[c0 + u + 2][r] = t.z; sKT[c0 + u + 3][r] = t.w;
                *(float4*)(&sV[r][c0 + u]) =
                    *(const float4*)(vp + (size_t)(bcol + r) * DD + c0 + u);
            }
        }
        __syncthreads();

        // S = fq @ fk^T (64x64x64), 4x4 per thread
        float s[4][4] = {};
        #pragma unroll 4
        for (int d = 0; d < 64; ++d) {
            float4 a = *(const float4*)(&sQT[d][ty * 4]);
            float4 b = *(const float4*)(&sKT[d][tx * 4]);
            float av[4] = {a.x, a.y, a.z, a.w};
            float bv[4] = {b.x, b.y, b.z, b.w};
            #pragma unroll
            for (int j = 0; j < 4; ++j)
                #pragma unroll
                for (int i = 0; i < 4; ++i)
                    s[j][i] = fmaf(av[j], bv[i], s[j][i]);
        }
        // causal mask on diagonal tile, then row-normalize
        if (ct == rblk) {
            #pragma unroll
            for (int j = 0; j < 4; ++j)
                #pragma unroll
                for (int i = 0; i < 4; ++i)
                    if (tx * 4 + i > ty * 4 + j) s[j][i] = 0.f;
        }
        #pragma unroll
        for (int j = 0; j < 4; ++j)
            #pragma unroll
            for (int i = 0; i < 4; ++i)
                s[j][i] *= rInv[j];

        // write attn tile (float4 per row) and stash transposed for PV
        #pragma unroll
        for (int j = 0; j < 4; ++j) {
            float4 o = {s[j][0], s[j][1], s[j][2], s[j][3]};
            *(float4*)(aout + (size_t)(ty * 4 + j) * LL + bcol + tx * 4) = o;
        }
        #pragma unroll
        for (int i = 0; i < 4; ++i) {
            float4 o = {s[0][i], s[1][i], s[2][i], s[3][i]};
            *(float4*)(&sS[tx * 4 + i][ty * 4]) = o;
        }
        __syncthreads();

        // PV: acc += S @ v
        #pragma unroll 4
        for (int c = 0; c < 64; ++c) {
            float4 a = *(const float4*)(&sS[c][ty * 4]);
            float4 b = *(const float4*)(&sV[c][tx * 4]);
            float av[4] = {a.x, a.y, a.z, a.w};
            float bv[4] = {b.x, b.y, b.z, b.w};
            #pragma unroll
            for (int j = 0; j < 4; ++j)
                #pragma unroll
                for (int i = 0; i < 4; ++i)
                    acc[j][i] = fmaf(av[j], bv[i], acc[j][i]);
        }
        __syncthreads();
    }

    // zero-fill attn tiles strictly above the diagonal
    for (int ct = rblk + 1; ct < NT; ++ct) {
        int bcol = ct * 64;
        float4 z = {0.f, 0.f, 0.f, 0.f};
        #pragma unroll
        for (int u = 0; u < 4; ++u) {
            int idx = tid + u * 256;        // float4 index in 64x64 tile
            int r = idx >> 4, c4 = idx & 15;
            *(float4*)(aout + (size_t)r * LL + bcol + c4 * 4) = z;
        }
    }

    // write out tile
    float* oo = outO + (size_t)bh * LL * DD + (size_t)brow * DD;
    #pragma unroll
    for (int j = 0; j < 4; ++j) {
        float4 o = {acc[j][0], acc[j][1], acc[j][2], acc[j][3]};
        *(float4*)(oo + (size_t)(ty * 4 + j) * DD + tx * 4) = o;
    }
}

// ---------------------------------------------------------------------------
extern "C" void kernel_launch(void* const* d_in, const int* in_sizes, int n_in,
                              void* d_out, int out_size, void* d_ws, size_t ws_size,
                              hipStream_t stream)
{
    (void)in_sizes; (void)n_in; (void)out_size; (void)ws_size;
    const float* q  = (const float*)d_in[0];
    const float* k  = (const float*)d_in[1];
    const float* v  = (const float*)d_in[2];
    const float* Wq = (const float*)d_in[3];   // fm_q_weight
    const float* Wk = (const float*)d_in[4];   // fm_k_weight

    float* out  = (float*)d_out;                       // [B,H,L,D]
    float* attn = out + (size_t)BB * HH * LL * DD;     // [B,H,L,L]

    float* FQ = (float*)d_ws;                          // [BH,L,D]
    float* FK = FQ + (size_t)BH * LL * DD;             // [BH,L,D]
    float* CS = FK + (size_t)BH * LL * DD;             // [BH,L,D]

    // NOTE the reference's swap: fq uses fm_k_weight, fk uses fm_q_weight.
    fmap_kernel<<<BH * NT, 256, 0, stream>>>(q, Wk, FQ);
    fmap_kernel<<<BH * NT, 256, 0, stream>>>(k, Wq, FK);
    csum_kernel<<<BH, 1024, 0, stream>>>(FK, CS);
    attn_kernel<<<BH * NT, 256, 0, stream>>>(FQ, FK, CS, v, out, attn);
}

// Round 4
// 300.389 us; speedup vs baseline: 1.7492x; 1.7492x over previous
//
#include <hip/hip_runtime.h>
#include <hip/hip_bf16.h>

// Problem constants (B,H,L,D = 2,16,2048,64)
#define BB 2
#define HH 16
#define LL 2048
#define DD 64
constexpr int BH = BB * HH;   // 32 heads
constexpr int NT = LL / 64;   // 32 tiles of 64

typedef __attribute__((ext_vector_type(8))) short bf16x8;  // 8 bf16 (4 VGPR)
typedef __attribute__((ext_vector_type(4))) float f32x4;   // 4 f32

typedef unsigned short u16;
typedef unsigned int u32;

__device__ __forceinline__ u16 f2bf(float x) {
    __bf16 b = (__bf16)x;          // RNE convert
    u16 u; __builtin_memcpy(&u, &b, 2);
    return u;
}
__device__ __forceinline__ float bf2f(u16 u) {
    union { u32 i; float f; } c; c.i = ((u32)u) << 16; return c.f;
}

// async global->LDS, 16B per lane; lds dest = wave-uniform base + lane*16
__device__ __forceinline__ void gll16(const void* gptr, void* ldsptr) {
    __builtin_amdgcn_global_load_lds(
        (const u32 __attribute__((address_space(1)))*)gptr,
        (u32 __attribute__((address_space(3)))*)ldsptr, 16, 0, 0);
}

// fragment read: one ds_read_b128 from a swizzled row-major [64][64] bf16 tile.
// element k of fragment = (lane>>4)*8 + i  (+ ks*32), row = free index.
__device__ __forceinline__ bf16x8 ld_frag(const char* tile, int row, int kbyte) {
    return *(const bf16x8*)(tile + row * 128 + (kbyte ^ ((row & 7) << 4)));
}

// ---------------------------------------------------------------------------
// fmap2: out_hi/lo = split-bf16(relu(x @ W)) per head, written as pre-swizzled
// 64x64 tiles (tile t = blockIdx.x = bh*32+rb, byte off = r*128 + (c*2 ^ ((r&7)<<4)))
// ---------------------------------------------------------------------------
__global__ __launch_bounds__(256) void fmap2_kernel(
    const float* __restrict__ x, const float* __restrict__ W,
    u16* __restrict__ ghi, u16* __restrict__ glo)
{
    __shared__ float sXT[64][64];
    __shared__ float sW[64][64];
    int bx = blockIdx.x;
    int bh = bx / NT, rb = bx % NT;
    int h = bh % HH;
    const float* xp = x + (size_t)bh * LL * DD + (size_t)rb * 64 * DD;
    const float* wp = W + (size_t)h * DD * DD;

    int tid = threadIdx.x;
    {
        int r = tid >> 2, c0 = (tid & 3) * 16;
        for (int u = 0; u < 16; u += 4) {
            float4 t = *(const float4*)(xp + r * DD + c0 + u);
            sXT[c0 + u + 0][r] = t.x; sXT[c0 + u + 1][r] = t.y;
            sXT[c0 + u + 2][r] = t.z; sXT[c0 + u + 3][r] = t.w;
            *(float4*)(&sW[r][c0 + u]) = *(const float4*)(wp + r * DD + c0 + u);
        }
    }
    __syncthreads();

    int ty = tid >> 4, tx = tid & 15;
    float acc[4][4] = {};
    #pragma unroll 4
    for (int d = 0; d < 64; ++d) {
        float4 a = *(const float4*)(&sXT[d][ty * 4]);
        float4 b = *(const float4*)(&sW[d][tx * 4]);
        float av[4] = {a.x, a.y, a.z, a.w};
        float bv[4] = {b.x, b.y, b.z, b.w};
        #pragma unroll
        for (int j = 0; j < 4; ++j)
            #pragma unroll
            for (int i = 0; i < 4; ++i)
                acc[j][i] = fmaf(av[j], bv[i], acc[j][i]);
    }

    char* hib = (char*)ghi + (size_t)bx * 8192;
    char* lob = (char*)glo + (size_t)bx * 8192;
    #pragma unroll
    for (int j = 0; j < 4; ++j) {
        int rr = ty * 4 + j;
        ushort4 hv, lv;
        float v0 = fmaxf(acc[j][0], 0.f), v1 = fmaxf(acc[j][1], 0.f);
        float v2 = fmaxf(acc[j][2], 0.f), v3 = fmaxf(acc[j][3], 0.f);
        hv.x = f2bf(v0); hv.y = f2bf(v1); hv.z = f2bf(v2); hv.w = f2bf(v3);
        lv.x = f2bf(v0 - bf2f(hv.x)); lv.y = f2bf(v1 - bf2f(hv.y));
        lv.z = f2bf(v2 - bf2f(hv.z)); lv.w = f2bf(v3 - bf2f(hv.w));
        int off = rr * 128 + ((tx * 8) ^ ((rr & 7) << 4));
        *(ushort4*)(hib + off) = hv;
        *(ushort4*)(lob + off) = lv;
    }
}

// ---------------------------------------------------------------------------
// vprep: V fp32 [c][e] -> VT bf16 swizzled tiles [e][c] (tile = bh*32+ct)
// ---------------------------------------------------------------------------
__global__ __launch_bounds__(256) void vprep_kernel(
    const float* __restrict__ v, u16* __restrict__ vt)
{
    int bx = blockIdx.x;
    int bh = bx >> 5, ct = bx & 31;
    int t = threadIdx.x;
    int c0 = (t >> 4) * 4, e0 = (t & 15) * 4;
    const float* vp = v + ((size_t)bh * LL + (size_t)ct * 64) * DD;

    float ld[4][4];
    #pragma unroll
    for (int j = 0; j < 4; ++j) {
        float4 f = *(const float4*)(vp + (size_t)(c0 + j) * DD + e0);
        ld[j][0] = f.x; ld[j][1] = f.y; ld[j][2] = f.z; ld[j][3] = f.w;
    }
    char* base = (char*)vt + (size_t)bx * 8192;
    #pragma unroll
    for (int i = 0; i < 4; ++i) {
        int e = e0 + i;
        ushort4 wv;
        wv.x = f2bf(ld[0][i]); wv.y = f2bf(ld[1][i]);
        wv.z = f2bf(ld[2][i]); wv.w = f2bf(ld[3][i]);
        *(ushort4*)(base + e * 128 + ((c0 * 2) ^ ((e & 7) << 4))) = wv;
    }
}

// ---------------------------------------------------------------------------
// csum2: rinv[bh][r] = 1 / ( fq_r . cumsum(fk)_r )   (reads hi/lo tiles)
// one block/head, 16 waves; lane = dim d, wave = 128-row chunk.
// ---------------------------------------------------------------------------
__global__ __launch_bounds__(1024) void csum2_kernel(
    const u16* __restrict__ khi, const u16* __restrict__ klo,
    const u16* __restrict__ qhi, const u16* __restrict__ qlo,
    float* __restrict__ rinv)
{
    __shared__ float chunk[16][64];
    int bh = blockIdx.x;
    int w = threadIdx.x >> 6, d = threadIdx.x & 63;
    const int CH = LL / 16;   // 128

    float s = 0.f;
    for (int i = 0; i < CH; ++i) {
        int r = w * CH + i;
        int idx = (bh * 32 + (r >> 6)) * 4096 + (r & 63) * 64 + (d ^ (((r & 63) & 7) << 3));
        s += bf2f(khi[idx]) + bf2f(klo[idx]);
    }
    chunk[w][d] = s;
    __syncthreads();
    float run = 0.f;
    for (int w2 = 0; w2 < w; ++w2) run += chunk[w2][d];

    for (int i = 0; i < CH; ++i) {
        int r = w * CH + i;
        int idx = (bh * 32 + (r >> 6)) * 4096 + (r & 63) * 64 + (d ^ (((r & 63) & 7) << 3));
        run += bf2f(khi[idx]) + bf2f(klo[idx]);
        float qv = bf2f(qhi[idx]) + bf2f(qlo[idx]);
        float t = qv * run;
        #pragma unroll
        for (int o = 1; o < 64; o <<= 1) t += __shfl_xor(t, o);
        if (d == 0) rinv[(size_t)bh * LL + r] = 1.0f / t;
    }
}

// ---------------------------------------------------------------------------
// attn2: MFMA split-bf16. Block = (bh, rblk), 4 waves.
// D1 = mfma(fk, fq) gives S^T quadrants; mask+normalize; attn store;
// S -> bf16 via wave-private LDS bounce; D2 = mfma(V^T, S^T) accumulates out^T.
// ---------------------------------------------------------------------------
__global__ __launch_bounds__(256) void attn2_kernel(
    const u16* __restrict__ qhi, const u16* __restrict__ qlo,
    const u16* __restrict__ khi, const u16* __restrict__ klo,
    const u16* __restrict__ vt, const float* __restrict__ rinvg,
    float* __restrict__ outO, float* __restrict__ outA)
{
    __shared__ __align__(16) char sQ[16384];   // hi [0,8K), lo [8K,16K)
    __shared__ __align__(16) char sK[16384];
    __shared__ __align__(16) char sVT[8192];
    __shared__ __align__(16) char sS[8192];

    int bx = blockIdx.x;
    // XCD-grouping: 4 consecutive heads per XCD; interleave long/short rblk
    int bh = (bx & 7) * 4 + (bx >> 8);
    int jj = (bx >> 3) & 31;
    int rblk = (jj & 1) ? (jj >> 1) : (31 - (jj >> 1));
    int brow = rblk * 64;

    int tid = threadIdx.x;
    int w = tid >> 6, l = tid & 63;
    int l15 = l & 15, lq = l >> 4;

    const char* qhiT = (const char*)qhi + ((size_t)bh * NT + rblk) * 8192;
    const char* qloT = (const char*)qlo + ((size_t)bh * NT + rblk) * 8192;

    {
        int o = tid * 16;
        gll16(qhiT + o,        sQ + (w << 10));
        gll16(qhiT + o + 4096, sQ + (w << 10) + 4096);
        gll16(qloT + o,        sQ + 8192 + (w << 10));
        gll16(qloT + o + 4096, sQ + 8192 + (w << 10) + 4096);
    }

    float ri = rinvg[(size_t)bh * LL + brow + w * 16 + l15];

    asm volatile("s_waitcnt vmcnt(0)" ::: "memory");
    __syncthreads();

    // persistent fq B-fragments (row = this lane's output row)
    int qrow = w * 16 + l15;
    bf16x8 bqh[2], bql[2];
    #pragma unroll
    for (int ks = 0; ks < 2; ++ks) {
        bqh[ks] = ld_frag(sQ,        qrow, lq * 16 + ks * 64);
        bql[ks] = ld_frag(sQ + 8192, qrow, lq * 16 + ks * 64);
    }

    f32x4 acc2[4];
    #pragma unroll
    for (int eb = 0; eb < 4; ++eb) acc2[eb] = (f32x4){0.f, 0.f, 0.f, 0.f};

    float* aoutrow = outA + ((size_t)bh * LL + brow + w * 16 + l15) * LL;

    for (int ct = 0; ct <= rblk; ++ct) {
        const char* khiT = (const char*)khi + ((size_t)bh * NT + ct) * 8192;
        const char* kloT = (const char*)klo + ((size_t)bh * NT + ct) * 8192;
        const char* vtT  = (const char*)vt  + ((size_t)bh * NT + ct) * 8192;
        {
            int o = tid * 16;
            gll16(khiT + o,        sK + (w << 10));
            gll16(khiT + o + 4096, sK + (w << 10) + 4096);
            gll16(kloT + o,        sK + 8192 + (w << 10));
            gll16(kloT + o + 4096, sK + 8192 + (w << 10) + 4096);
            gll16(vtT + o,         sVT + (w << 10));
            gll16(vtT + o + 4096,  sVT + (w << 10) + 4096);
        }
        asm volatile("s_waitcnt vmcnt(0)" ::: "memory");
        __syncthreads();

        // QK^T: S^T quadrants, 3-pass split bf16
        f32x4 sa[4];
        #pragma unroll
        for (int cb = 0; cb < 4; ++cb) sa[cb] = (f32x4){0.f, 0.f, 0.f, 0.f};
        #pragma unroll
        for (int ks = 0; ks < 2; ++ks) {
            #pragma unroll
            for (int cb = 0; cb < 4; ++cb) {
                int krow = cb * 16 + l15;
                bf16x8 ah = ld_frag(sK,        krow, lq * 16 + ks * 64);
                bf16x8 al = ld_frag(sK + 8192, krow, lq * 16 + ks * 64);
                sa[cb] = __builtin_amdgcn_mfma_f32_16x16x32_bf16(ah, bqh[ks], sa[cb], 0, 0, 0);
                sa[cb] = __builtin_amdgcn_mfma_f32_16x16x32_bf16(ah, bql[ks], sa[cb], 0, 0, 0);
                sa[cb] = __builtin_amdgcn_mfma_f32_16x16x32_bf16(al, bqh[ks], sa[cb], 0, 0, 0);
            }
        }

        int bcol = ct * 64;
        bool diag = (ct == rblk);
        #pragma unroll
        for (int cb = 0; cb < 4; ++cb) {
            if (diag) {
                #pragma unroll
                for (int rg = 0; rg < 4; ++rg)
                    if (cb * 16 + lq * 4 + rg > w * 16 + l15) sa[cb][rg] = 0.f;
            }
            sa[cb] *= ri;
            __builtin_nontemporal_store(sa[cb],
                (f32x4*)(aoutrow + bcol + cb * 16 + lq * 4));
        }

        // S -> bf16 via wave-private LDS stripe (no barrier needed)
        {
            int srow = w * 16 + l15;
            #pragma unroll
            for (int cb = 0; cb < 4; ++cb) {
                ushort4 pv;
                pv.x = f2bf(sa[cb][0]); pv.y = f2bf(sa[cb][1]);
                pv.z = f2bf(sa[cb][2]); pv.w = f2bf(sa[cb][3]);
                int off = srow * 128 + ((cb * 32 + lq * 8) ^ ((srow & 7) << 4));
                *(ushort4*)(sS + off) = pv;
            }
        }
        bf16x8 pf[2];
        #pragma unroll
        for (int ks = 0; ks < 2; ++ks)
            pf[ks] = ld_frag(sS, w * 16 + l15, lq * 16 + ks * 64);

        // PV: out^T += V^T @ S^T
        #pragma unroll
        for (int ks = 0; ks < 2; ++ks) {
            #pragma unroll
            for (int eb = 0; eb < 4; ++eb) {
                bf16x8 av = ld_frag(sVT, eb * 16 + l15, lq * 16 + ks * 64);
                acc2[eb] = __builtin_amdgcn_mfma_f32_16x16x32_bf16(av, pf[ks], acc2[eb], 0, 0, 0);
            }
        }
        __syncthreads();   // protect sK/sVT before next stage
    }

    // zero-fill strictly-above-diagonal attn tiles
    f32x4 z = {0.f, 0.f, 0.f, 0.f};
    for (int ct2 = rblk + 1; ct2 < NT; ++ct2) {
        int bcol = ct2 * 64;
        #pragma unroll
        for (int u = 0; u < 4; ++u) {
            int idx = tid + u * 256;
            int r = idx >> 4, c4 = idx & 15;
            __builtin_nontemporal_store(z,
                (f32x4*)(outA + ((size_t)bh * LL + brow + r) * LL + bcol + c4 * 4));
        }
    }

    // out write (from out^T accumulators)
    float* oo = outO + ((size_t)bh * LL + brow + w * 16 + l15) * DD;
    #pragma unroll
    for (int eb = 0; eb < 4; ++eb) {
        float4 o = { acc2[eb][0], acc2[eb][1], acc2[eb][2], acc2[eb][3] };
        *(float4*)(oo + eb * 16 + lq * 4) = o;
    }
}

// ---------------------------------------------------------------------------
extern "C" void kernel_launch(void* const* d_in, const int* in_sizes, int n_in,
                              void* d_out, int out_size, void* d_ws, size_t ws_size,
                              hipStream_t stream)
{
    (void)in_sizes; (void)n_in; (void)out_size; (void)ws_size;
    const float* q  = (const float*)d_in[0];
    const float* k  = (const float*)d_in[1];
    const float* v  = (const float*)d_in[2];
    const float* Wq = (const float*)d_in[3];
    const float* Wk = (const float*)d_in[4];

    float* out  = (float*)d_out;                       // [B,H,L,D]
    float* attn = out + (size_t)BB * HH * LL * DD;     // [B,H,L,L]

    const size_t TILE_HW = (size_t)BH * NT * 4096;     // halfwords per bf16 array
    u16* QHI = (u16*)d_ws;
    u16* QLO = QHI + TILE_HW;
    u16* KHI = QLO + TILE_HW;
    u16* KLO = KHI + TILE_HW;
    u16* VT  = KLO + TILE_HW;
    float* RINV = (float*)(VT + TILE_HW);              // [BH, L]

    // NOTE reference swap: fq uses fm_k_weight, fk uses fm_q_weight.
    fmap2_kernel<<<BH * NT, 256, 0, stream>>>(q, Wk, QHI, QLO);
    fmap2_kernel<<<BH * NT, 256, 0, stream>>>(k, Wq, KHI, KLO);
    vprep_kernel<<<BH * NT, 256, 0, stream>>>(v, VT);
    csum2_kernel<<<BH, 1024, 0, stream>>>(KHI, KLO, QHI, QLO, RINV);
    attn2_kernel<<<BH * NT, 256, 0, stream>>>(QHI, QLO, KHI, KLO, VT, RINV, out, attn);
}

// Round 5
// 169.173 us; speedup vs baseline: 3.1060x; 1.7756x over previous
//
#include <hip/hip_runtime.h>
#include <hip/hip_bf16.h>

// Problem constants (B,H,L,D = 2,16,2048,64)
#define BB 2
#define HH 16
#define LL 2048
#define DD 64
constexpr int BH = BB * HH;   // 32 heads
constexpr int NT = LL / 64;   // 32 tiles of 64

typedef __attribute__((ext_vector_type(8))) short bf16x8;  // 8 bf16 (4 VGPR)
typedef __attribute__((ext_vector_type(4))) float f32x4;   // 4 f32

typedef unsigned short u16;
typedef unsigned int u32;

__device__ __forceinline__ u16 f2bf(float x) {
    __bf16 b = (__bf16)x;          // RNE convert
    u16 u; __builtin_memcpy(&u, &b, 2);
    return u;
}
__device__ __forceinline__ float bf2f(u16 u) {
    union { u32 i; float f; } c; c.i = ((u32)u) << 16; return c.f;
}

// async global->LDS, 16B per lane; lds dest = wave-uniform base + lane*16
__device__ __forceinline__ void gll16(const void* gptr, void* ldsptr) {
    __builtin_amdgcn_global_load_lds(
        (const u32 __attribute__((address_space(1)))*)gptr,
        (u32 __attribute__((address_space(3)))*)ldsptr, 16, 0, 0);
}

// fragment read: one ds_read_b128 from a swizzled row-major [64][64] bf16 tile.
__device__ __forceinline__ bf16x8 ld_frag(const char* tile, int row, int kbyte) {
    return *(const bf16x8*)(tile + row * 128 + (kbyte ^ ((row & 7) << 4)));
}

// ---------------------------------------------------------------------------
// fmap2: hi/lo = split-bf16(relu(x @ W)) per head, pre-swizzled 64x64 tiles.
// TSUM: additionally emit per-tile per-dim column sums of the relu'd values.
// ---------------------------------------------------------------------------
template<bool TSUM>
__global__ __launch_bounds__(256) void fmap2_kernel(
    const float* __restrict__ x, const float* __restrict__ W,
    u16* __restrict__ ghi, u16* __restrict__ glo, float* __restrict__ tsum)
{
    __shared__ float sXT[64][64];
    __shared__ float sW[64][64];
    int bx = blockIdx.x;
    int bh = bx / NT, rb = bx % NT;
    int h = bh % HH;
    const float* xp = x + (size_t)bh * LL * DD + (size_t)rb * 64 * DD;
    const float* wp = W + (size_t)h * DD * DD;

    int tid = threadIdx.x;
    {
        int r = tid >> 2, c0 = (tid & 3) * 16;
        for (int u = 0; u < 16; u += 4) {
            float4 t = *(const float4*)(xp + r * DD + c0 + u);
            sXT[c0 + u + 0][r] = t.x; sXT[c0 + u + 1][r] = t.y;
            sXT[c0 + u + 2][r] = t.z; sXT[c0 + u + 3][r] = t.w;
            *(float4*)(&sW[r][c0 + u]) = *(const float4*)(wp + r * DD + c0 + u);
        }
    }
    __syncthreads();

    int ty = tid >> 4, tx = tid & 15;
    float acc[4][4] = {};
    #pragma unroll 4
    for (int d = 0; d < 64; ++d) {
        float4 a = *(const float4*)(&sXT[d][ty * 4]);
        float4 b = *(const float4*)(&sW[d][tx * 4]);
        float av[4] = {a.x, a.y, a.z, a.w};
        float bv[4] = {b.x, b.y, b.z, b.w};
        #pragma unroll
        for (int j = 0; j < 4; ++j)
            #pragma unroll
            for (int i = 0; i < 4; ++i)
                acc[j][i] = fmaf(av[j], bv[i], acc[j][i]);
    }

    float rv[4][4];
    #pragma unroll
    for (int j = 0; j < 4; ++j)
        #pragma unroll
        for (int i = 0; i < 4; ++i)
            rv[j][i] = fmaxf(acc[j][i], 0.f);

    char* hib = (char*)ghi + (size_t)bx * 8192;
    char* lob = (char*)glo + (size_t)bx * 8192;
    #pragma unroll
    for (int j = 0; j < 4; ++j) {
        int rr = ty * 4 + j;
        ushort4 hv, lv;
        hv.x = f2bf(rv[j][0]); hv.y = f2bf(rv[j][1]);
        hv.z = f2bf(rv[j][2]); hv.w = f2bf(rv[j][3]);
        lv.x = f2bf(rv[j][0] - bf2f(hv.x)); lv.y = f2bf(rv[j][1] - bf2f(hv.y));
        lv.z = f2bf(rv[j][2] - bf2f(hv.z)); lv.w = f2bf(rv[j][3] - bf2f(hv.w));
        int off = rr * 128 + ((tx * 8) ^ ((rr & 7) << 4));
        *(ushort4*)(hib + off) = hv;
        *(ushort4*)(lob + off) = lv;
    }

    if constexpr (TSUM) {
        __syncthreads();           // safe to reuse sXT
        #pragma unroll
        for (int i = 0; i < 4; ++i)
            sXT[ty][tx * 4 + i] = rv[0][i] + rv[1][i] + rv[2][i] + rv[3][i];
        __syncthreads();
        if (tid < 64) {
            float s = 0.f;
            #pragma unroll
            for (int y = 0; y < 16; ++y) s += sXT[y][tid];
            tsum[(size_t)bx * 64 + tid] = s;
        }
    }
}

// ---------------------------------------------------------------------------
// vprep: V fp32 [c][e] -> VT bf16 swizzled tiles [e][c]
// ---------------------------------------------------------------------------
__global__ __launch_bounds__(256) void vprep_kernel(
    const float* __restrict__ v, u16* __restrict__ vt)
{
    int bx = blockIdx.x;
    int bh = bx >> 5, ct = bx & 31;
    int t = threadIdx.x;
    int c0 = (t >> 4) * 4, e0 = (t & 15) * 4;
    const float* vp = v + ((size_t)bh * LL + (size_t)ct * 64) * DD;

    float ld[4][4];
    #pragma unroll
    for (int j = 0; j < 4; ++j) {
        float4 f = *(const float4*)(vp + (size_t)(c0 + j) * DD + e0);
        ld[j][0] = f.x; ld[j][1] = f.y; ld[j][2] = f.z; ld[j][3] = f.w;
    }
    char* base = (char*)vt + (size_t)bx * 8192;
    #pragma unroll
    for (int i = 0; i < 4; ++i) {
        int e = e0 + i;
        ushort4 wv;
        wv.x = f2bf(ld[0][i]); wv.y = f2bf(ld[1][i]);
        wv.z = f2bf(ld[2][i]); wv.w = f2bf(ld[3][i]);
        *(ushort4*)(base + e * 128 + ((c0 * 2) ^ ((e & 7) << 4))) = wv;
    }
}

// ---------------------------------------------------------------------------
// tprefix: per-head exclusive prefix over the 32 per-tile sums. 32 blk x 64 thr.
// ---------------------------------------------------------------------------
__global__ __launch_bounds__(64) void tprefix_kernel(
    const float* __restrict__ tsum, float* __restrict__ pex)
{
    int bh = blockIdx.x, d = threadIdx.x;
    float run = 0.f;
    for (int t = 0; t < NT; ++t) {
        size_t i = ((size_t)bh * NT + t) * 64 + d;
        pex[i] = run;
        run += tsum[i];
    }
}

// ---------------------------------------------------------------------------
// rowsum: rinv[bh][r] = 1 / (fq_r . cumsum(fk)_r). 1024 blocks, 4 waves each;
// wave w owns 16 rows of the tile; lane = dim.
// ---------------------------------------------------------------------------
__global__ __launch_bounds__(256) void rowsum_kernel(
    const u16* __restrict__ khi, const u16* __restrict__ klo,
    const u16* __restrict__ qhi, const u16* __restrict__ qlo,
    const float* __restrict__ pex, float* __restrict__ rinv)
{
    __shared__ float wsum[4][64];
    int bx = blockIdx.x;
    int bh = bx >> 5, t = bx & 31;
    int w = threadIdx.x >> 6, d = threadIdx.x & 63;
    const size_t tb = ((size_t)bh * NT + t) * 4096;

    float fkv[16];
    float s = 0.f;
    #pragma unroll
    for (int i = 0; i < 16; ++i) {
        int r = w * 16 + i;
        size_t idx = tb + r * 64 + (d ^ ((r & 7) << 3));
        fkv[i] = bf2f(khi[idx]) + bf2f(klo[idx]);
        s += fkv[i];
    }
    wsum[w][d] = s;
    __syncthreads();

    float cs = pex[((size_t)bh * NT + t) * 64 + d];
    for (int w2 = 0; w2 < w; ++w2) cs += wsum[w2][d];

    #pragma unroll
    for (int i = 0; i < 16; ++i) {
        int r = w * 16 + i;
        size_t idx = tb + r * 64 + (d ^ ((r & 7) << 3));
        cs += fkv[i];
        float tt = (bf2f(qhi[idx]) + bf2f(qlo[idx])) * cs;
        #pragma unroll
        for (int o = 1; o < 64; o <<= 1) tt += __shfl_xor(tt, o);
        if (d == 0) rinv[(size_t)bh * LL + t * 64 + r] = 1.0f / tt;
    }
}

// ---------------------------------------------------------------------------
// attn3: double-buffered MFMA kernel.
// LDS: buf0[24K: Khi|Klo|VT] buf1[24K] sS[8K].  2 blocks/CU.
// Per tile: stage(t+1) -> QK^T(split bf16) -> mask/normalize -> sS(bf16) ->
// raw barrier -> coop full-line attn store + PV -> __syncthreads.
// ---------------------------------------------------------------------------
__global__ __launch_bounds__(256) void attn3_kernel(
    const u16* __restrict__ qhi, const u16* __restrict__ qlo,
    const u16* __restrict__ khi, const u16* __restrict__ klo,
    const u16* __restrict__ vt, const float* __restrict__ rinvg,
    float* __restrict__ outO, float* __restrict__ outA)
{
    __shared__ __align__(16) char lds[57344];
    char* sS = lds + 49152;

    int bx = blockIdx.x;
    // XCD-grouping: 4 consecutive heads per XCD; interleave long/short rblk
    int bh = (bx & 7) * 4 + (bx >> 8);
    int jj = (bx >> 3) & 31;
    int rblk = (jj & 1) ? (jj >> 1) : (31 - (jj >> 1));
    int brow = rblk * 64;

    int tid = threadIdx.x;
    int w = tid >> 6, l = tid & 63;
    int l15 = l & 15, lq = l >> 4;
    int o = tid * 16, wb = w << 10;

    // ---- prologue: stage Q -> buf1 area, tile0 -> buf0 ----
    {
        const char* qhiT = (const char*)qhi + ((size_t)bh * NT + rblk) * 8192;
        const char* qloT = (const char*)qlo + ((size_t)bh * NT + rblk) * 8192;
        gll16(qhiT + o,        lds + 24576 + wb);
        gll16(qhiT + o + 4096, lds + 24576 + wb + 4096);
        gll16(qloT + o,        lds + 24576 + 8192 + wb);
        gll16(qloT + o + 4096, lds + 24576 + 8192 + wb + 4096);

        const char* khiT = (const char*)khi + (size_t)bh * NT * 8192;
        const char* kloT = (const char*)klo + (size_t)bh * NT * 8192;
        const char* vtT  = (const char*)vt  + (size_t)bh * NT * 8192;
        gll16(khiT + o,        lds + wb);
        gll16(khiT + o + 4096, lds + wb + 4096);
        gll16(kloT + o,        lds + 8192 + wb);
        gll16(kloT + o + 4096, lds + 8192 + wb + 4096);
        gll16(vtT + o,         lds + 16384 + wb);
        gll16(vtT + o + 4096,  lds + 16384 + wb + 4096);
    }
    float ri = rinvg[(size_t)bh * LL + brow + w * 16 + l15];
    asm volatile("s_waitcnt vmcnt(0)" ::: "memory");
    __syncthreads();

    // Q fragments to registers
    int qrow = w * 16 + l15;
    bf16x8 bqh[2], bql[2];
    #pragma unroll
    for (int ks = 0; ks < 2; ++ks) {
        bqh[ks] = ld_frag(lds + 24576,        qrow, lq * 16 + ks * 64);
        bql[ks] = ld_frag(lds + 24576 + 8192, qrow, lq * 16 + ks * 64);
    }
    __syncthreads();   // Q region safe to reuse as buf1

    f32x4 acc2[4];
    #pragma unroll
    for (int eb = 0; eb < 4; ++eb) acc2[eb] = (f32x4){0.f, 0.f, 0.f, 0.f};

    for (int ct = 0; ct <= rblk; ++ct) {
        char* cur = lds + (ct & 1) * 24576;

        if (ct < rblk) {   // stage next tile into the other buffer
            char* nxt = lds + ((ct + 1) & 1) * 24576;
            const char* khiT = (const char*)khi + ((size_t)bh * NT + ct + 1) * 8192;
            const char* kloT = (const char*)klo + ((size_t)bh * NT + ct + 1) * 8192;
            const char* vtT  = (const char*)vt  + ((size_t)bh * NT + ct + 1) * 8192;
            gll16(khiT + o,        nxt + wb);
            gll16(khiT + o + 4096, nxt + wb + 4096);
            gll16(kloT + o,        nxt + 8192 + wb);
            gll16(kloT + o + 4096, nxt + 8192 + wb + 4096);
            gll16(vtT + o,         nxt + 16384 + wb);
            gll16(vtT + o + 4096,  nxt + 16384 + wb + 4096);
        }

        // QK^T: S^T quadrants, 3-pass split bf16
        f32x4 sa[4];
        #pragma unroll
        for (int cb = 0; cb < 4; ++cb) sa[cb] = (f32x4){0.f, 0.f, 0.f, 0.f};
        #pragma unroll
        for (int ks = 0; ks < 2; ++ks) {
            #pragma unroll
            for (int cb = 0; cb < 4; ++cb) {
                int krow = cb * 16 + l15;
                bf16x8 ah = ld_frag(cur,        krow, lq * 16 + ks * 64);
                bf16x8 al = ld_frag(cur + 8192, krow, lq * 16 + ks * 64);
                sa[cb] = __builtin_amdgcn_mfma_f32_16x16x32_bf16(ah, bqh[ks], sa[cb], 0, 0, 0);
                sa[cb] = __builtin_amdgcn_mfma_f32_16x16x32_bf16(ah, bql[ks], sa[cb], 0, 0, 0);
                sa[cb] = __builtin_amdgcn_mfma_f32_16x16x32_bf16(al, bqh[ks], sa[cb], 0, 0, 0);
            }
        }

        bool diag = (ct == rblk);
        int srow = w * 16 + l15;
        #pragma unroll
        for (int cb = 0; cb < 4; ++cb) {
            if (diag) {
                #pragma unroll
                for (int rg = 0; rg < 4; ++rg)
                    if (cb * 16 + lq * 4 + rg > srow) sa[cb][rg] = 0.f;
            }
            sa[cb] *= ri;
            ushort4 pv;
            pv.x = f2bf(sa[cb][0]); pv.y = f2bf(sa[cb][1]);
            pv.z = f2bf(sa[cb][2]); pv.w = f2bf(sa[cb][3]);
            int soff = srow * 128 + ((cb * 32 + lq * 8) ^ ((srow & 7) << 4));
            *(ushort4*)(sS + soff) = pv;
        }

        // make sS visible to all waves WITHOUT draining vmcnt (stage in flight)
        asm volatile("s_waitcnt lgkmcnt(0)" ::: "memory");
        __builtin_amdgcn_sched_barrier(0);
        __builtin_amdgcn_s_barrier();
        __builtin_amdgcn_sched_barrier(0);

        // cooperative full-line attn store: 16 lanes cover one row's 256B
        {
            int bcol = ct * 64;
            float* atile = outA + ((size_t)bh * LL + brow) * LL + bcol;
            #pragma unroll
            for (int u = 0; u < 4; ++u) {
                int idx = tid + u * 256;
                int r = idx >> 4;
                int c = idx & 15;
                ushort4 pv = *(const ushort4*)(sS + r * 128 + ((c * 8) ^ ((r & 7) << 4)));
                f32x4 o4 = { bf2f(pv.x), bf2f(pv.y), bf2f(pv.z), bf2f(pv.w) };
                __builtin_nontemporal_store(o4, (f32x4*)(atile + (size_t)r * LL + c * 4));
            }
        }

        // PV: out^T += V^T @ S^T
        bf16x8 pf[2];
        #pragma unroll
        for (int ks = 0; ks < 2; ++ks)
            pf[ks] = ld_frag(sS, srow, lq * 16 + ks * 64);
        #pragma unroll
        for (int ks = 0; ks < 2; ++ks) {
            #pragma unroll
            for (int eb = 0; eb < 4; ++eb) {
                bf16x8 av = ld_frag(cur + 16384, eb * 16 + l15, lq * 16 + ks * 64);
                acc2[eb] = __builtin_amdgcn_mfma_f32_16x16x32_bf16(av, pf[ks], acc2[eb], 0, 0, 0);
            }
        }

        __syncthreads();   // drain (stage latency already hidden) + buffer handoff
    }

    // zero-fill strictly-above-diagonal attn tiles (full-line coalesced)
    f32x4 z = {0.f, 0.f, 0.f, 0.f};
    for (int ct2 = rblk + 1; ct2 < NT; ++ct2) {
        int bcol = ct2 * 64;
        #pragma unroll
        for (int u = 0; u < 4; ++u) {
            int idx = tid + u * 256;
            int r = idx >> 4, c4 = idx & 15;
            __builtin_nontemporal_store(z,
                (f32x4*)(outA + ((size_t)bh * LL + brow + r) * LL + bcol + c4 * 4));
        }
    }

    // out write (from out^T accumulators)
    float* oo = outO + ((size_t)bh * LL + brow + w * 16 + l15) * DD;
    #pragma unroll
    for (int eb = 0; eb < 4; ++eb) {
        float4 o4 = { acc2[eb][0], acc2[eb][1], acc2[eb][2], acc2[eb][3] };
        *(float4*)(oo + eb * 16 + lq * 4) = o4;
    }
}

// ---------------------------------------------------------------------------
extern "C" void kernel_launch(void* const* d_in, const int* in_sizes, int n_in,
                              void* d_out, int out_size, void* d_ws, size_t ws_size,
                              hipStream_t stream)
{
    (void)in_sizes; (void)n_in; (void)out_size; (void)ws_size;
    const float* q  = (const float*)d_in[0];
    const float* k  = (const float*)d_in[1];
    const float* v  = (const float*)d_in[2];
    const float* Wq = (const float*)d_in[3];
    const float* Wk = (const float*)d_in[4];

    float* out  = (float*)d_out;                       // [B,H,L,D]
    float* attn = out + (size_t)BB * HH * LL * DD;     // [B,H,L,L]

    const size_t TILE_HW = (size_t)BH * NT * 4096;     // halfwords per bf16 array
    u16* QHI = (u16*)d_ws;
    u16* QLO = QHI + TILE_HW;
    u16* KHI = QLO + TILE_HW;
    u16* KLO = KHI + TILE_HW;
    u16* VT  = KLO + TILE_HW;
    float* RINV = (float*)(VT + TILE_HW);              // [BH, L]
    float* TSUM = RINV + (size_t)BH * LL;              // [BH, NT, 64]
    float* PEX  = TSUM + (size_t)BH * NT * 64;         // [BH, NT, 64]

    // NOTE reference swap: fq uses fm_k_weight, fk uses fm_q_weight.
    fmap2_kernel<false><<<BH * NT, 256, 0, stream>>>(q, Wk, QHI, QLO, nullptr);
    fmap2_kernel<true><<<BH * NT, 256, 0, stream>>>(k, Wq, KHI, KLO, TSUM);
    vprep_kernel<<<BH * NT, 256, 0, stream>>>(v, VT);
    tprefix_kernel<<<BH, 64, 0, stream>>>(TSUM, PEX);
    rowsum_kernel<<<BH * NT, 256, 0, stream>>>(KHI, KLO, QHI, QLO, PEX, RINV);
    attn3_kernel<<<BH * NT, 256, 0, stream>>>(QHI, QLO, KHI, KLO, VT, RINV, out, attn);
}